// Round 2
// baseline (420.865 us; speedup 1.0000x reference)
//
#include <hip/hip_runtime.h>

static constexpr int NN = 100000;    // nodes
static constexpr int EE = 1600000;   // edges (before self-loops)
static constexpr int BSZ = 64;       // nodes per bucket
static constexpr int NB = (NN + BSZ - 1) / BSZ;   // 1563 buckets
static constexpr int BCAP = 2048;    // fixed bucket capacity (mean 1024, 32 sigma)
static constexpr int TILE = 2048;    // edges per binning block
static constexpr int GB = 2048;      // gather blocks (persistent: 8 blocks/CU, 1 dispatch wave)

// ---- bf16 helpers (storage-only; math stays fp32) ----

__device__ __forceinline__ unsigned short f2bf(float f) {   // round-to-nearest-even
    unsigned u = __float_as_uint(f);
    u += 0x7FFFu + ((u >> 16) & 1u);
    return (unsigned short)(u >> 16);
}
__device__ __forceinline__ float bfl(unsigned u) { return __uint_as_float(u << 16); }
__device__ __forceinline__ float bfh(unsigned u) { return __uint_as_float(u & 0xFFFF0000u); }

typedef __attribute__((ext_vector_type(8))) short short8;    // 8 bf16 (4 VGPRs)
typedef __attribute__((ext_vector_type(4))) float float4v;   // MFMA acc
typedef __attribute__((ext_vector_type(4))) float float4n;   // nt-store vector

// ---------------- init: W^T bf16 prep + bucket cursor bases ----------------

__global__ __launch_bounds__(256) void k_init(const float* __restrict__ W1,
                                              const float* __restrict__ W2,
                                              unsigned short* __restrict__ W1t,
                                              unsigned short* __restrict__ W2t,
                                              int* __restrict__ bcur) {
    int idx = blockIdx.x * 256 + threadIdx.x;
    if (idx < 16384) {
        int n = idx >> 7, k = idx & 127;
        W1t[idx] = f2bf(W1[k * 128 + n]);
    } else if (idx < 24576) {
        int j = idx - 16384;
        int n = j >> 7, k = j & 127;
        W2t[j] = f2bf(W2[k * 64 + n]);
    } else if (idx < 24576 + NB) {
        int b = idx - 24576;
        bcur[b] = b * BCAP;
    }
}

// ---------------- bin edges into fixed-stride bucket chunks ----------------

__global__ __launch_bounds__(256) void k_bin(const int* __restrict__ src,
                                             const int* __restrict__ dst,
                                             int* __restrict__ bcur,
                                             int* __restrict__ ebuf, int E) {
    constexpr int K = TILE / 256;  // 8 edges per thread
    __shared__ int lcnt[NB];
    __shared__ int lbase[NB];
    const int t = threadIdx.x;
    const int e0 = blockIdx.x * TILE;

    for (int i = t; i < NB; i += 256) lcnt[i] = 0;
    __syncthreads();

    int dreg[K], ofs[K];
#pragma unroll
    for (int k = 0; k < K; ++k) {
        int e = e0 + k * 256 + t;
        if (e < E) {
            int d = dst[e];
            dreg[k] = d;
            ofs[k] = atomicAdd(&lcnt[d >> 6], 1);
        } else dreg[k] = -1;
    }
    __syncthreads();

    for (int i = t; i < NB; i += 256) {
        int c = lcnt[i];
        lbase[i] = c ? atomicAdd(&bcur[i], c) : 0;
    }
    __syncthreads();

#pragma unroll
    for (int k = 0; k < K; ++k) {
        if (dreg[k] >= 0) {
            int e = e0 + k * 256 + t;
            int s = src[e];
            int b = dreg[k] >> 6;
            ebuf[lbase[b] + ofs[k]] = (s << 6) | (dreg[k] & 63);
        }
    }
}

// ---------------- per-bucket: counts, rbe (beg,end), dinv, CSR scatter -----

__global__ __launch_bounds__(256) void k_csr(const int* __restrict__ bcur,
                                             const int* __restrict__ ebuf,
                                             int2* __restrict__ rbe,
                                             float* __restrict__ dinv,
                                             int* __restrict__ csr, int n) {
    __shared__ int lcnt[BSZ];
    __shared__ int lofs[BSZ];
    const int b = blockIdx.x, t = threadIdx.x;
    if (t < BSZ) lcnt[t] = 0;
    __syncthreads();
    const int beg = b * BCAP, end = bcur[b];
    for (int j = beg + t; j < end; j += 256) atomicAdd(&lcnt[ebuf[j] & 63], 1);
    __syncthreads();
    if (t < BSZ) {                       // wave 0 only (threads 0..63)
        int c = lcnt[t];
        int x = c;
#pragma unroll
        for (int off = 1; off < 64; off <<= 1) {
            int y = __shfl_up(x, off, 64);
            if (t >= off) x += y;
        }
        int exc = x - c;                 // exclusive prefix within bucket
        int node = b * BSZ + t;
        if (node < n) {
            rbe[node] = make_int2(beg + exc, beg + exc + c);
            dinv[node] = rsqrtf((float)c + 1.0f);   // +1 self-loop
        }
        lofs[t] = beg + exc;
    }
    __syncthreads();
    for (int j = beg + t; j < end; j += 256) {
        int e = ebuf[j];
        int pos = atomicAdd(&lofs[e & 63], 1);
        csr[pos] = e >> 6;
    }
}

// ---------------- MFMA GEMM layer 1: G = bf16((X @ W1) * dinv[row]) --------
// Output SLAB-MAJOR: 8 slabs of 16 cols; slab s = [N][4] uint2 (32 B/row).

__global__ __launch_bounds__(256) void k_gemm128m(const float* __restrict__ X,
                                                  const unsigned short* __restrict__ W1t,
                                                  const float* __restrict__ dinv,
                                                  unsigned* __restrict__ G, int M) {
    __shared__ float cls[4 * 16 * 132];
    const int t = threadIdx.x;
    const int w = t >> 6, lane = t & 63;
    const int quad = lane >> 4, m16 = lane & 15;
    const int row0 = blockIdx.x * 64 + w * 16;
    int arow = row0 + m16; if (arow >= M) arow = M - 1;

    short8 afrag[4];
#pragma unroll
    for (int ks = 0; ks < 4; ++ks) {
        const float* p = X + (size_t)arow * 128 + ks * 32 + quad * 8;
        float4 u0 = ((const float4*)p)[0];
        float4 u1 = ((const float4*)p)[1];
        short8 a;
        a[0] = (short)f2bf(u0.x); a[1] = (short)f2bf(u0.y);
        a[2] = (short)f2bf(u0.z); a[3] = (short)f2bf(u0.w);
        a[4] = (short)f2bf(u1.x); a[5] = (short)f2bf(u1.y);
        a[6] = (short)f2bf(u1.z); a[7] = (short)f2bf(u1.w);
        afrag[ks] = a;
    }
    float* myc = cls + w * 16 * 132;
#pragma unroll
    for (int nt = 0; nt < 8; ++nt) {
        float4v acc = {0.f, 0.f, 0.f, 0.f};
#pragma unroll
        for (int ks = 0; ks < 4; ++ks) {
            const short8 b = *((const short8*)(W1t + (size_t)(nt * 16 + m16) * 128 + ks * 32 + quad * 8));
            acc = __builtin_amdgcn_mfma_f32_16x16x32_bf16(afrag[ks], b, acc, 0, 0, 0);
        }
#pragma unroll
        for (int r = 0; r < 4; ++r)
            myc[(quad * 4 + r) * 132 + nt * 16 + m16] = acc[r];
    }
    __syncthreads();
    // pack + store into slab-major layout: slab = c>>2, chunk = c&3
#pragma unroll
    for (int i = 0; i < 8; ++i) {
        int idx = i * 64 + lane;
        int r = idx >> 5, c = idx & 31;
        int grow = row0 + r;
        if (grow < M) {
            float4 v = *((const float4*)(myc + r * 132 + c * 4));
            float s = dinv[grow];
            uint2 p;
            p.x = (unsigned)f2bf(v.x * s) | ((unsigned)f2bf(v.y * s) << 16);
            p.y = (unsigned)f2bf(v.z * s) | ((unsigned)f2bf(v.w * s) << 16);
            ((uint2*)G)[(size_t)(c >> 2) * NN * 4 + (size_t)grow * 4 + (c & 3)] = p;
        }
    }
}

// ---------------- MFMA GEMM layer 2: G = bf16((Xbf16 @ W2) * dinv[row]) ----
// A read from slab-major h1 (8 slabs x [N][16] bf16); output 4 slabs of 16 cols.

__global__ __launch_bounds__(256) void k_gemm64m(const unsigned short* __restrict__ X,
                                                 const unsigned short* __restrict__ W2t,
                                                 const float* __restrict__ dinv,
                                                 unsigned* __restrict__ G, int M) {
    __shared__ float cls[4 * 16 * 68];
    const int t = threadIdx.x;
    const int w = t >> 6, lane = t & 63;
    const int quad = lane >> 4, m16 = lane & 15;
    const int row0 = blockIdx.x * 64 + w * 16;
    int arow = row0 + m16; if (arow >= M) arow = M - 1;

    short8 afrag[4];
#pragma unroll
    for (int ks = 0; ks < 4; ++ks) {
        const int slab = 2 * ks + (quad >> 1);     // cols ks*32+quad*8 -> slab of 16
        afrag[ks] = *((const short8*)(X + (size_t)slab * NN * 16 + (size_t)arow * 16 + (quad & 1) * 8));
    }

    float* myc = cls + w * 16 * 68;
#pragma unroll
    for (int nt = 0; nt < 4; ++nt) {
        float4v acc = {0.f, 0.f, 0.f, 0.f};
#pragma unroll
        for (int ks = 0; ks < 4; ++ks) {
            const short8 b = *((const short8*)(W2t + (size_t)(nt * 16 + m16) * 128 + ks * 32 + quad * 8));
            acc = __builtin_amdgcn_mfma_f32_16x16x32_bf16(afrag[ks], b, acc, 0, 0, 0);
        }
#pragma unroll
        for (int r = 0; r < 4; ++r)
            myc[(quad * 4 + r) * 68 + nt * 16 + m16] = acc[r];
    }
    __syncthreads();
#pragma unroll
    for (int i = 0; i < 4; ++i) {
        int idx = i * 64 + lane;
        int r = idx >> 4, c = idx & 15;
        int grow = row0 + r;
        if (grow < M) {
            float4 v = *((const float4*)(myc + r * 68 + c * 4));
            float s = dinv[grow];
            uint2 p;
            p.x = (unsigned)f2bf(v.x * s) | ((unsigned)f2bf(v.y * s) << 16);
            p.y = (unsigned)f2bf(v.z * s) | ((unsigned)f2bf(v.w * s) << 16);
            ((uint2*)G)[(size_t)(c >> 2) * NN * 4 + (size_t)grow * 4 + (c & 3)] = p;
        }
    }
}

// ---------------- sliced gather + fused epilogue ---------------------------
// Feature-sliced: slab of 16 cols (32 B/row) is L2-RESIDENT on one XCD
// (slab = blockIdx&7 -> XCD via round-robin dispatch; 3.2 MB < 4 MB L2).
// Wave = 4 nodes (16 lanes each); 4 lanes x uint2 per edge -> 16 edges per
// load instruction, 4 steps unrolled (deg<=64 in flight).  rbe prefetched
// 2 iterations ahead, first csr block 1 iteration ahead (hides L3 latency).
// csr/rbe nt-loads + nt-stores keep the slab resident.

__device__ __forceinline__ int2 ld_rbe(const int2* __restrict__ rbe, int node, int n) {
    int2 r = make_int2(0, 0);
    if (node < n) {
        long long v = __builtin_nontemporal_load((const long long*)(rbe + node));
        r.x = (int)(v & 0xffffffffll);
        r.y = (int)(v >> 32);
    }
    return r;
}
__device__ __forceinline__ int ld_csr(const int* __restrict__ csr, int2 re, int off) {
    int deg = re.y - re.x;
    int v = __builtin_nontemporal_load(csr + re.x + ((off < deg) ? off : 0));
    return (deg > 0) ? v : 0;   // deg==0: force src=0 (csr slot may be unwritten)
}

template<int LAYER>
__global__ __launch_bounds__(256) void k_gather_s(
        const int2* __restrict__ rbe, const int* __restrict__ csr,
        const unsigned* __restrict__ Gall, const float* __restrict__ dinv,
        const float* __restrict__ bias, unsigned* __restrict__ OUT, int n) {
    const int lane = threadIdx.x & 63;
    const int w = threadIdx.x >> 6;
    const int q = lane >> 4;                  // node slot 0..3
    const int l16 = lane & 15;
    const int g4 = (lane >> 2) & 3;           // edge slot within quarter
    const int sub = lane & 3;                 // uint2 chunk within 32-B slice
    const int shbase = (lane & 48) | g4;      // shfl source base: q*16 + g4

    int slice, wis, stride;
    if (LAYER == 1) {                         // 8 slabs, 1 XCD each
        slice = blockIdx.x & 7;
        wis = (blockIdx.x >> 3) * 4 + w;
        stride = (GB / 8) * 4;                // 1024 waves per slice
    } else {                                  // 4 slabs, 2 XCDs each
        slice = (blockIdx.x & 7) >> 1;
        wis = (blockIdx.x >> 3) * 8 + (blockIdx.x & 1) * 4 + w;
        stride = (GB / 8) * 8;                // 2048 waves per slice
    }
    const int iter_nodes = stride * 4;
    const uint2* slab = (const uint2*)(Gall + (size_t)slice * NN * 8);  // [N][4] uint2

    int node = wis * 4 + q;
    int2 re_cur = ld_rbe(rbe, node, n);
    int2 re_nx  = ld_rbe(rbe, node + iter_nodes, n);
    int idx_cur = ld_csr(csr, re_cur, l16);

    for (; node < n; node += iter_nodes) {
        const int2 re = re_cur;
        int idx = idx_cur;
        re_cur = re_nx;                                   // rotate pipeline
        re_nx  = ld_rbe(rbe, node + 2 * iter_nodes, n);
        idx_cur = ld_csr(csr, re_cur, l16);

        const int deg = re.y - re.x;
        float a0 = 0.f, a1 = 0.f, a2 = 0.f, a3 = 0.f;
        for (int eo = 0; eo < BCAP; ) {                   // hard-bounded
#pragma unroll
            for (int st = 0; st < 4; ++st) {              // 4 independent loads in flight
                int e = eo + st * 4 + g4;
                int s = __shfl(idx, shbase | (st << 2), 64);
                uint2 v = slab[(size_t)s * 4 + sub];
                if (e < deg) { a0 += bfl(v.x); a1 += bfh(v.x); a2 += bfl(v.y); a3 += bfh(v.y); }
            }
            eo += 16;
            if (!__any(eo < deg)) break;
            idx = ld_csr(csr, re, eo + l16);
        }
        // reduce across the 4 edge slots (lane bits 2..3)
        a0 += __shfl_xor(a0, 4, 64); a0 += __shfl_xor(a0, 8, 64);
        a1 += __shfl_xor(a1, 4, 64); a1 += __shfl_xor(a1, 8, 64);
        a2 += __shfl_xor(a2, 4, 64); a2 += __shfl_xor(a2, 8, 64);
        a3 += __shfl_xor(a3, 4, 64); a3 += __shfl_xor(a3, 8, 64);
        if (g4 == 0) {
            uint2 vs = slab[(size_t)node * 4 + sub];      // self-loop
            a0 += bfl(vs.x); a1 += bfh(vs.x); a2 += bfl(vs.y); a3 += bfh(vs.y);
            const float di = dinv[node];
            const float4 bv = ((const float4*)bias)[slice * 4 + sub];
            float r0 = fmaf(a0, di, bv.x), r1 = fmaf(a1, di, bv.y);
            float r2 = fmaf(a2, di, bv.z), r3 = fmaf(a3, di, bv.w);
            if (LAYER == 1) {
                r0 = fmaxf(r0, 0.f); r1 = fmaxf(r1, 0.f);
                r2 = fmaxf(r2, 0.f); r3 = fmaxf(r3, 0.f);
                unsigned lo = (unsigned)f2bf(r0) | ((unsigned)f2bf(r1) << 16);
                unsigned hi = (unsigned)f2bf(r2) | ((unsigned)f2bf(r3) << 16);
                unsigned long long p = (unsigned long long)lo | ((unsigned long long)hi << 32);
                __builtin_nontemporal_store(p,
                    (unsigned long long*)((uint2*)OUT + (size_t)slice * NN * 4 + (size_t)node * 4 + sub));
            } else {
                float4n r = {r0, r1, r2, r3};
                __builtin_nontemporal_store(r,
                    (float4n*)OUT + (size_t)node * 16 + slice * 4 + sub);
            }
        }
    }
}

// ---------------- launch ----------------

extern "C" void kernel_launch(void* const* d_in, const int* in_sizes, int n_in,
                              void* d_out, int out_size, void* d_ws, size_t ws_size,
                              hipStream_t stream) {
    const float* x  = (const float*)d_in[0];
    const float* W1 = (const float*)d_in[1];
    const float* b1 = (const float*)d_in[2];
    const float* W2 = (const float*)d_in[3];
    const float* b2 = (const float*)d_in[4];
    const int*   ei = (const int*)d_in[5];   // [2, E] int32
    const int* src = ei;
    const int* dst = ei + EE;
    float* out = (float*)d_out;

    // ws layout (16-B aligned slabs first):
    unsigned* g1b = (unsigned*)d_ws;                     // N*64 u : 8 slabs x [N][8]u
    unsigned* h1b = g1b + (size_t)NN * 64;               // N*64 u : 8 slabs x [N][16] bf16
    unsigned* g2b = h1b + (size_t)NN * 64;               // N*32 u : 4 slabs x [N][8]u
    unsigned short* w1t = (unsigned short*)(g2b + (size_t)NN * 32);  // 16384 bf16
    unsigned short* w2t = w1t + 16384;                   // 8192 bf16
    int2*  rbe  = (int2*)(w2t + 8192);                   // N int2 (beg,end)
    float* dinv = (float*)(rbe + NN);                    // N
    int*   bcur = (int*)(dinv + NN);                     // NB
    int*   ebuf = bcur + NB;                             // NB*BCAP
    int*   csr  = ebuf + (size_t)NB * BCAP;              // NB*BCAP

    constexpr int IB = (24576 + NB + 255) / 256;  // init blocks

    k_init<<<IB, 256, 0, stream>>>(W1, W2, w1t, w2t, bcur);
    k_bin<<<(EE + TILE - 1) / TILE, 256, 0, stream>>>(src, dst, bcur, ebuf, EE);
    k_csr<<<NB, 256, 0, stream>>>(bcur, ebuf, rbe, dinv, csr, NN);

    // layer 1: g1b = bf16((x@W1)*dinv) ; h1b = bf16(relu(dinv*(agg+g1)+b1))
    k_gemm128m<<<(NN + 63) / 64, 256, 0, stream>>>(x, w1t, dinv, g1b, NN);
    k_gather_s<1><<<GB, 256, 0, stream>>>(rbe, csr, g1b, dinv, b1, h1b, NN);

    // layer 2: g2b = bf16((h1b@W2)*dinv) ; out = dinv*(agg+g2)+b2  [fp32]
    k_gemm64m<<<(NN + 63) / 64, 256, 0, stream>>>((const unsigned short*)h1b, w2t, dinv, g2b, NN);
    k_gather_s<2><<<GB, 256, 0, stream>>>(rbe, csr, g2b, dinv, b2, (unsigned*)out, NN);
}

// Round 3
// 350.674 us; speedup vs baseline: 1.2002x; 1.2002x over previous
//
#include <hip/hip_runtime.h>

static constexpr int NN = 100000;    // nodes
static constexpr int EE = 1600000;   // edges (before self-loops)
static constexpr int BSZ = 64;       // nodes per bucket
static constexpr int NB = (NN + BSZ - 1) / BSZ;   // 1563 buckets
static constexpr int BCAP = 2048;    // fixed bucket capacity (mean 1024, 32 sigma)
static constexpr int TILE = 2048;    // edges per binning block
static constexpr int GB = 2048;      // gather blocks (persistent: 8 blocks/CU, 1 dispatch wave)

// ---- bf16 helpers (storage-only; math stays fp32) ----

__device__ __forceinline__ unsigned short f2bf(float f) {   // round-to-nearest-even
    unsigned u = __float_as_uint(f);
    u += 0x7FFFu + ((u >> 16) & 1u);
    return (unsigned short)(u >> 16);
}
__device__ __forceinline__ float bfl(unsigned u) { return __uint_as_float(u << 16); }
__device__ __forceinline__ float bfh(unsigned u) { return __uint_as_float(u & 0xFFFF0000u); }

typedef __attribute__((ext_vector_type(8))) short short8;    // 8 bf16 (4 VGPRs)
typedef __attribute__((ext_vector_type(4))) float float4v;   // MFMA acc
typedef __attribute__((ext_vector_type(4))) float float4n;   // nt-store vector

// ---------------- init: W^T bf16 prep + bucket cursor bases ----------------

__global__ __launch_bounds__(256) void k_init(const float* __restrict__ W1,
                                              const float* __restrict__ W2,
                                              unsigned short* __restrict__ W1t,
                                              unsigned short* __restrict__ W2t,
                                              int* __restrict__ bcur) {
    int idx = blockIdx.x * 256 + threadIdx.x;
    if (idx < 16384) {
        int n = idx >> 7, k = idx & 127;
        W1t[idx] = f2bf(W1[k * 128 + n]);
    } else if (idx < 24576) {
        int j = idx - 16384;
        int n = j >> 7, k = j & 127;
        W2t[j] = f2bf(W2[k * 64 + n]);
    } else if (idx < 24576 + NB) {
        int b = idx - 24576;
        bcur[b] = b * BCAP;
    }
}

// ---------------- bin edges into fixed-stride bucket chunks ----------------

__global__ __launch_bounds__(256) void k_bin(const int* __restrict__ src,
                                             const int* __restrict__ dst,
                                             int* __restrict__ bcur,
                                             int* __restrict__ ebuf, int E) {
    constexpr int K = TILE / 256;  // 8 edges per thread
    __shared__ int lcnt[NB];
    __shared__ int lbase[NB];
    const int t = threadIdx.x;
    const int e0 = blockIdx.x * TILE;

    for (int i = t; i < NB; i += 256) lcnt[i] = 0;
    __syncthreads();

    int dreg[K], ofs[K];
#pragma unroll
    for (int k = 0; k < K; ++k) {
        int e = e0 + k * 256 + t;
        if (e < E) {
            int d = dst[e];
            dreg[k] = d;
            ofs[k] = atomicAdd(&lcnt[d >> 6], 1);
        } else dreg[k] = -1;
    }
    __syncthreads();

    for (int i = t; i < NB; i += 256) {
        int c = lcnt[i];
        lbase[i] = c ? atomicAdd(&bcur[i], c) : 0;
    }
    __syncthreads();

#pragma unroll
    for (int k = 0; k < K; ++k) {
        if (dreg[k] >= 0) {
            int e = e0 + k * 256 + t;
            int s = src[e];
            int b = dreg[k] >> 6;
            ebuf[lbase[b] + ofs[k]] = (s << 6) | (dreg[k] & 63);
        }
    }
}

// ---------------- per-bucket: counts, rbe (beg,end), dinv, CSR scatter -----

__global__ __launch_bounds__(256) void k_csr(const int* __restrict__ bcur,
                                             const int* __restrict__ ebuf,
                                             int2* __restrict__ rbe,
                                             float* __restrict__ dinv,
                                             int* __restrict__ csr, int n) {
    __shared__ int lcnt[BSZ];
    __shared__ int lofs[BSZ];
    const int b = blockIdx.x, t = threadIdx.x;
    if (t < BSZ) lcnt[t] = 0;
    __syncthreads();
    const int beg = b * BCAP, end = bcur[b];
    for (int j = beg + t; j < end; j += 256) atomicAdd(&lcnt[ebuf[j] & 63], 1);
    __syncthreads();
    if (t < BSZ) {                       // wave 0 only (threads 0..63)
        int c = lcnt[t];
        int x = c;
#pragma unroll
        for (int off = 1; off < 64; off <<= 1) {
            int y = __shfl_up(x, off, 64);
            if (t >= off) x += y;
        }
        int exc = x - c;                 // exclusive prefix within bucket
        int node = b * BSZ + t;
        if (node < n) {
            rbe[node] = make_int2(beg + exc, beg + exc + c);
            dinv[node] = rsqrtf((float)c + 1.0f);   // +1 self-loop
        }
        lofs[t] = beg + exc;
    }
    __syncthreads();
    for (int j = beg + t; j < end; j += 256) {
        int e = ebuf[j];
        int pos = atomicAdd(&lofs[e & 63], 1);
        csr[pos] = e >> 6;
    }
}

// ---------------- MFMA GEMM layer 1: G = bf16((X @ W1) * dinv[row]) --------
// Output SLAB-MAJOR: 4 slabs of 32 cols; slab s = [N][8] uint2 (64 B/row).

__global__ __launch_bounds__(256) void k_gemm128m(const float* __restrict__ X,
                                                  const unsigned short* __restrict__ W1t,
                                                  const float* __restrict__ dinv,
                                                  unsigned* __restrict__ G, int M) {
    __shared__ float cls[4 * 16 * 132];
    const int t = threadIdx.x;
    const int w = t >> 6, lane = t & 63;
    const int quad = lane >> 4, m16 = lane & 15;
    const int row0 = blockIdx.x * 64 + w * 16;
    int arow = row0 + m16; if (arow >= M) arow = M - 1;

    short8 afrag[4];
#pragma unroll
    for (int ks = 0; ks < 4; ++ks) {
        const float* p = X + (size_t)arow * 128 + ks * 32 + quad * 8;
        float4 u0 = ((const float4*)p)[0];
        float4 u1 = ((const float4*)p)[1];
        short8 a;
        a[0] = (short)f2bf(u0.x); a[1] = (short)f2bf(u0.y);
        a[2] = (short)f2bf(u0.z); a[3] = (short)f2bf(u0.w);
        a[4] = (short)f2bf(u1.x); a[5] = (short)f2bf(u1.y);
        a[6] = (short)f2bf(u1.z); a[7] = (short)f2bf(u1.w);
        afrag[ks] = a;
    }
    float* myc = cls + w * 16 * 132;
#pragma unroll
    for (int nt = 0; nt < 8; ++nt) {
        float4v acc = {0.f, 0.f, 0.f, 0.f};
#pragma unroll
        for (int ks = 0; ks < 4; ++ks) {
            const short8 b = *((const short8*)(W1t + (size_t)(nt * 16 + m16) * 128 + ks * 32 + quad * 8));
            acc = __builtin_amdgcn_mfma_f32_16x16x32_bf16(afrag[ks], b, acc, 0, 0, 0);
        }
#pragma unroll
        for (int r = 0; r < 4; ++r)
            myc[(quad * 4 + r) * 132 + nt * 16 + m16] = acc[r];
    }
    __syncthreads();
    // pack + store into slab-major layout: slab = c>>3, chunk = c&7
#pragma unroll
    for (int i = 0; i < 8; ++i) {
        int idx = i * 64 + lane;
        int r = idx >> 5, c = idx & 31;
        int grow = row0 + r;
        if (grow < M) {
            float4 v = *((const float4*)(myc + r * 132 + c * 4));
            float s = dinv[grow];
            uint2 p;
            p.x = (unsigned)f2bf(v.x * s) | ((unsigned)f2bf(v.y * s) << 16);
            p.y = (unsigned)f2bf(v.z * s) | ((unsigned)f2bf(v.w * s) << 16);
            ((uint2*)G)[(size_t)(c >> 3) * NN * 8 + (size_t)grow * 8 + (c & 7)] = p;
        }
    }
}

// ---------------- MFMA GEMM layer 2: G = bf16((Xbf16 @ W2) * dinv[row]) ----
// A read from slab-major h1 (4 slabs x [N][32] bf16); output 2 slabs of 32 cols.

__global__ __launch_bounds__(256) void k_gemm64m(const unsigned short* __restrict__ X,
                                                 const unsigned short* __restrict__ W2t,
                                                 const float* __restrict__ dinv,
                                                 unsigned* __restrict__ G, int M) {
    __shared__ float cls[4 * 16 * 68];
    const int t = threadIdx.x;
    const int w = t >> 6, lane = t & 63;
    const int quad = lane >> 4, m16 = lane & 15;
    const int row0 = blockIdx.x * 64 + w * 16;
    int arow = row0 + m16; if (arow >= M) arow = M - 1;

    short8 afrag[4];
#pragma unroll
    for (int ks = 0; ks < 4; ++ks)      // cols ks*32 + quad*8: slab = ks
        afrag[ks] = *((const short8*)(X + (size_t)ks * NN * 32 + (size_t)arow * 32 + quad * 8));

    float* myc = cls + w * 16 * 68;
#pragma unroll
    for (int nt = 0; nt < 4; ++nt) {
        float4v acc = {0.f, 0.f, 0.f, 0.f};
#pragma unroll
        for (int ks = 0; ks < 4; ++ks) {
            const short8 b = *((const short8*)(W2t + (size_t)(nt * 16 + m16) * 128 + ks * 32 + quad * 8));
            acc = __builtin_amdgcn_mfma_f32_16x16x32_bf16(afrag[ks], b, acc, 0, 0, 0);
        }
#pragma unroll
        for (int r = 0; r < 4; ++r)
            myc[(quad * 4 + r) * 68 + nt * 16 + m16] = acc[r];
    }
    __syncthreads();
#pragma unroll
    for (int i = 0; i < 4; ++i) {
        int idx = i * 64 + lane;
        int r = idx >> 4, c = idx & 15;
        int grow = row0 + r;
        if (grow < M) {
            float4 v = *((const float4*)(myc + r * 68 + c * 4));
            float s = dinv[grow];
            uint2 p;
            p.x = (unsigned)f2bf(v.x * s) | ((unsigned)f2bf(v.y * s) << 16);
            p.y = (unsigned)f2bf(v.z * s) | ((unsigned)f2bf(v.w * s) << 16);
            ((uint2*)G)[(size_t)(c >> 3) * NN * 8 + (size_t)grow * 8 + (c & 7)] = p;
        }
    }
}

// ---------------- sliced gather + fused epilogue ---------------------------
// 32-col slices (64-B rows): slab = 6.4 MB shared by an XCD pair (L1) or quad
// (L2 layer) -> ~62% L2 hit, 64-B requests (2x fewer, 2x bigger than 16-col).
// Wave = 4 nodes (16 lanes each); 8 lanes x uint2 per edge; 2 edge slots/node
// per step; group = 4 steps = 8 edges/node; __any-exit at 8-edge granularity.
// BOTH 16-edge csr windows preloaded (2nd predicated on deg>16) -> no serial
// csr latency for deg<=32 (99.99% of Poisson-16 nodes).

__device__ __forceinline__ int2 ld_rbe(const int2* __restrict__ rbe, int node, int n) {
    int2 r = make_int2(0, 0);
    if (node < n) {
        long long v = __builtin_nontemporal_load((const long long*)(rbe + node));
        r.x = (int)(v & 0xffffffffll);
        r.y = (int)(v >> 32);
    }
    return r;
}
__device__ __forceinline__ int ld_csr(const int* __restrict__ csr, int2 re, int off) {
    int deg = re.y - re.x;
    int v = __builtin_nontemporal_load(csr + re.x + ((off < deg) ? off : 0));
    return (deg > 0) ? v : 0;   // deg==0: force src=0 (csr slot may be unwritten)
}

template<int LAYER>
__global__ __launch_bounds__(256) void k_gather_s(
        const int2* __restrict__ rbe, const int* __restrict__ csr,
        const unsigned* __restrict__ Gall, const float* __restrict__ dinv,
        const float* __restrict__ bias, unsigned* __restrict__ OUT, int n) {
    const int lane = threadIdx.x & 63;
    const int w = threadIdx.x >> 6;
    const int l16 = lane & 15;
    const int g2 = (lane >> 3) & 1;           // edge slot within node (0..1)
    const int sub = lane & 7;                 // uint2 chunk within 64-B slice

    int slice, wis, stride;
    if (LAYER == 1) {                         // 4 slabs, XCD pair each
        slice = (blockIdx.x & 7) >> 1;
        wis = (blockIdx.x >> 3) * 8 + (blockIdx.x & 1) * 4 + w;
        stride = (GB / 8) * 8;                // 2048 waves per slice
    } else {                                  // 2 slabs, XCD quad each
        slice = (blockIdx.x & 7) >> 2;
        wis = (blockIdx.x >> 3) * 16 + (blockIdx.x & 3) * 4 + w;
        stride = (GB / 8) * 16;               // 4096 waves per slice
    }
    const int iter_nodes = stride * 4;
    const uint2* slab = (const uint2*)(Gall + (size_t)slice * NN * 16);  // [N][8] uint2

    int node = wis * 4 + (lane >> 4);
    int2 re_cur = ld_rbe(rbe, node, n);
    int2 re_nx  = ld_rbe(rbe, node + iter_nodes, n);
    int idx_cur = ld_csr(csr, re_cur, l16);

    for (; node < n; node += iter_nodes) {
        const int2 re = re_cur;
        int idx = idx_cur;
        re_cur = re_nx;                                   // rotate pipeline
        re_nx  = ld_rbe(rbe, node + 2 * iter_nodes, n);
        idx_cur = ld_csr(csr, re_cur, l16);

        const int deg = re.y - re.x;
        int idx2 = (deg > 16) ? ld_csr(csr, re, 16 + l16) : 0;  // window 1 preload

        float a0 = 0.f, a1 = 0.f, a2 = 0.f, a3 = 0.f;
        int wb = 0;
        bool done = false;
        while (!done) {
#pragma unroll
            for (int half = 0; half < 2 && !done; ++half) {
                const int hbase = wb + half * 16;
                const int hidx = half ? idx2 : idx;
#pragma unroll
                for (int g = 0; g < 2 && !done; ++g) {
#pragma unroll
                    for (int st = 0; st < 4; ++st) {      // 4 independent loads
                        int ew = g * 8 + st * 2 + g2;     // 0..15 within window
                        int e = hbase + ew;
                        int s = __shfl(hidx, (lane & 48) | ew, 64);
                        uint2 v = slab[(size_t)s * 8 + sub];
                        if (e < deg) { a0 += bfl(v.x); a1 += bfh(v.x);
                                       a2 += bfl(v.y); a3 += bfh(v.y); }
                    }
                    if (!__any(hbase + (g + 1) * 8 < deg)) done = true;
                }
            }
            if (!done) {
                wb += 32;
                if (wb >= BCAP) break;                    // hard bound
                idx  = ld_csr(csr, re, wb + l16);         // rare: deg > 32
                idx2 = (deg > wb + 16) ? ld_csr(csr, re, wb + 16 + l16) : 0;
            }
        }
        // reduce across the 2 edge slots (lane bit 3)
        a0 += __shfl_xor(a0, 8, 64);
        a1 += __shfl_xor(a1, 8, 64);
        a2 += __shfl_xor(a2, 8, 64);
        a3 += __shfl_xor(a3, 8, 64);
        if (g2 == 0) {
            uint2 vs = slab[(size_t)node * 8 + sub];      // self-loop
            a0 += bfl(vs.x); a1 += bfh(vs.x); a2 += bfl(vs.y); a3 += bfh(vs.y);
            const float di = dinv[node];
            const float4 bv = ((const float4*)bias)[slice * 8 + sub];
            float r0 = fmaf(a0, di, bv.x), r1 = fmaf(a1, di, bv.y);
            float r2 = fmaf(a2, di, bv.z), r3 = fmaf(a3, di, bv.w);
            if (LAYER == 1) {
                r0 = fmaxf(r0, 0.f); r1 = fmaxf(r1, 0.f);
                r2 = fmaxf(r2, 0.f); r3 = fmaxf(r3, 0.f);
                unsigned lo = (unsigned)f2bf(r0) | ((unsigned)f2bf(r1) << 16);
                unsigned hi = (unsigned)f2bf(r2) | ((unsigned)f2bf(r3) << 16);
                unsigned long long p = (unsigned long long)lo | ((unsigned long long)hi << 32);
                __builtin_nontemporal_store(p,
                    (unsigned long long*)((uint2*)OUT + (size_t)slice * NN * 8 + (size_t)node * 8 + sub));
            } else {
                float4n r = {r0, r1, r2, r3};
                __builtin_nontemporal_store(r,
                    (float4n*)OUT + (size_t)node * 16 + slice * 8 + sub);
            }
        }
    }
}

// ---------------- launch ----------------

extern "C" void kernel_launch(void* const* d_in, const int* in_sizes, int n_in,
                              void* d_out, int out_size, void* d_ws, size_t ws_size,
                              hipStream_t stream) {
    const float* x  = (const float*)d_in[0];
    const float* W1 = (const float*)d_in[1];
    const float* b1 = (const float*)d_in[2];
    const float* W2 = (const float*)d_in[3];
    const float* b2 = (const float*)d_in[4];
    const int*   ei = (const int*)d_in[5];   // [2, E] int32
    const int* src = ei;
    const int* dst = ei + EE;
    float* out = (float*)d_out;

    // ws layout (16-B aligned slabs first):
    unsigned* g1b = (unsigned*)d_ws;                     // N*64 u : 4 slabs x [N][8]uint2
    unsigned* h1b = g1b + (size_t)NN * 64;               // N*64 u : 4 slabs x [N][32] bf16
    unsigned* g2b = h1b + (size_t)NN * 64;               // N*32 u : 2 slabs x [N][8]uint2
    unsigned short* w1t = (unsigned short*)(g2b + (size_t)NN * 32);  // 16384 bf16
    unsigned short* w2t = w1t + 16384;                   // 8192 bf16
    int2*  rbe  = (int2*)(w2t + 8192);                   // N int2 (beg,end)
    float* dinv = (float*)(rbe + NN);                    // N
    int*   bcur = (int*)(dinv + NN);                     // NB
    int*   ebuf = bcur + NB;                             // NB*BCAP
    int*   csr  = ebuf + (size_t)NB * BCAP;              // NB*BCAP

    constexpr int IB = (24576 + NB + 255) / 256;  // init blocks

    k_init<<<IB, 256, 0, stream>>>(W1, W2, w1t, w2t, bcur);
    k_bin<<<(EE + TILE - 1) / TILE, 256, 0, stream>>>(src, dst, bcur, ebuf, EE);
    k_csr<<<NB, 256, 0, stream>>>(bcur, ebuf, rbe, dinv, csr, NN);

    // layer 1: g1b = bf16((x@W1)*dinv) ; h1b = bf16(relu(dinv*(agg+g1)+b1))
    k_gemm128m<<<(NN + 63) / 64, 256, 0, stream>>>(x, w1t, dinv, g1b, NN);
    k_gather_s<1><<<GB, 256, 0, stream>>>(rbe, csr, g1b, dinv, b1, h1b, NN);

    // layer 2: g2b = bf16((h1b@W2)*dinv) ; out = dinv*(agg+g2)+b2  [fp32]
    k_gemm64m<<<(NN + 63) / 64, 256, 0, stream>>>((const unsigned short*)h1b, w2t, dinv, g2b, NN);
    k_gather_s<2><<<GB, 256, 0, stream>>>(rbe, csr, g2b, dinv, b2, (unsigned*)out, NN);
}